// Round 2
// baseline (1433.929 us; speedup 1.0000x reference)
//
#include <hip/hip_runtime.h>

#define WSZ 8
#define NHE 4
#define CH 64
#define NT 64   // tokens per window
#define HD 16

// One block per window. 256 threads = 4 waves; wave w handles head w in the
// attention phase. All intermediates live in LDS in channel-major [C][N]
// layout: lane-indexed accesses (addr = c*64 + lane) are conflict-free, and
// per-m accesses in the attention loop are wave-uniform broadcasts.
// LDS: 4 * 64*64*4B = 64 KiB exactly -> 2 blocks/CU.
__global__ __launch_bounds__(256, 2) void win_attn(
    const float* __restrict__ x, const float* __restrict__ nw, const float* __restrict__ nb,
    const float* __restrict__ qkvw, const float* __restrict__ projw,
    const float* __restrict__ ascale, const float* __restrict__ rpb,
    float* __restrict__ out, int B, int H, int W)
{
    const int nww = W / WSZ;
    const int nwh = H / WSZ;
    const int win = blockIdx.x;
    const int ww = win % nww;
    const int t1 = win / nww;
    const int wh = t1 % nwh;
    const int b  = t1 / nwh;

    const int tid  = threadIdx.x;
    const int lane = tid & 63;
    const int wave = tid >> 6;

    __shared__ float xs[CH][NT];   // x window (normalized in place); later: attn output
    __shared__ float qs[CH][NT];
    __shared__ float ks[CH][NT];
    __shared__ float vs[CH][NT];

    const int rowbase = (wh * WSZ) * W + ww * WSZ;

    // ---- load x window -> xs[c][t] (channel-major) ----
    for (int e = tid; e < NT * CH; e += 256) {
        const int c = e >> 6;
        const int t = e & 63;
        const int i = t >> 3, j = t & 7;
        xs[c][t] = x[(b * CH + c) * H * W + rowbase + i * W + j];
    }
    __syncthreads();

    // ---- LayerNorm over channels, one thread per token ----
    if (tid < NT) {
        float s = 0.f, s2 = 0.f;
        #pragma unroll
        for (int c = 0; c < CH; c++) { float v = xs[c][tid]; s += v; s2 += v * v; }
        const float mu  = s * (1.f / CH);
        const float var = s2 * (1.f / CH) - mu * mu;
        const float rs  = rsqrtf(var + 1e-5f);
        #pragma unroll
        for (int c = 0; c < CH; c++) {
            xs[c][tid] = (xs[c][tid] - mu) * rs * nw[c] + nb[c];
        }
    }
    __syncthreads();

    // ---- QKV projection: y[n][r] = sum_c xn[n][c] * qkvw[r][c] ----
    // thread (wave,lane): token n=lane, rows r = jj*4 + wave (wave-uniform r)
    {
        float xr[CH];
        #pragma unroll
        for (int c = 0; c < CH; c++) xr[c] = xs[c][lane];
        for (int jj = 0; jj < 48; jj++) {
            const int r = jj * 4 + wave;
            const float* wr = qkvw + r * CH;
            float acc = 0.f;
            #pragma unroll
            for (int c = 0; c < CH; c++) acc += xr[c] * wr[c];
            const int which = r >> 6;      // 0:q 1:k 2:v (wave-uniform)
            const int ch    = r & 63;
            float* dst = (which == 0) ? &qs[ch][lane]
                       : (which == 1) ? &ks[ch][lane]
                                      : &vs[ch][lane];
            *dst = acc;
        }
    }
    __syncthreads();

    // ---- attention: wave = head h; lane = query token n ----
    {
        const int h = wave;
        float q[HD];
        #pragma unroll
        for (int d = 0; d < HD; d++) q[d] = qs[h * HD + d][lane];

        float sc[NT];
        const int i1 = lane >> 3, j1 = lane & 7;
        float mx = -1e30f;
        #pragma unroll
        for (int m = 0; m < NT; m++) {
            float s = 0.f;
            #pragma unroll
            for (int d = 0; d < HD; d++) s += q[d] * ks[h * HD + d][m];
            const int i2 = m >> 3, j2 = m & 7;
            const int rpi = (i1 - i2 + 7) * 15 + (j1 - j2 + 7);
            s = s * 0.25f + rpb[rpi * NHE + h];   // hd^-0.5 = 0.25
            sc[m] = s;
            mx = fmaxf(mx, s);
        }
        float sum = 0.f;
        #pragma unroll
        for (int m = 0; m < NT; m++) { float e = __expf(sc[m] - mx); sc[m] = e; sum += e; }
        const float inv = 1.f / sum;

        float o[HD];
        #pragma unroll
        for (int d = 0; d < HD; d++) o[d] = 0.f;
        #pragma unroll
        for (int m = 0; m < NT; m++) {
            const float p = sc[m] * inv;
            #pragma unroll
            for (int d = 0; d < HD; d++) o[d] += p * vs[h * HD + d][m];
        }
        // xs is dead after the QKV phase's barrier; reuse it for attn output
        #pragma unroll
        for (int d = 0; d < HD; d++) xs[h * HD + d][lane] = o[d];
    }
    __syncthreads();

    // ---- output proj + residual: y = x + ascale * (o @ projw^T) ----
    {
        float orow[CH];
        #pragma unroll
        for (int cc = 0; cc < CH; cc++) orow[cc] = xs[cc][lane];
        const float asc = ascale[0];
        const int i = lane >> 3, j = lane & 7;
        for (int cq = 0; cq < 16; cq++) {
            const int c = wave * 16 + cq;   // wave-uniform channel
            const float* pr = projw + c * CH;
            float acc = 0.f;
            #pragma unroll
            for (int cc = 0; cc < CH; cc++) acc += orow[cc] * pr[cc];
            const int gidx = (b * CH + c) * H * W + rowbase + i * W + j;
            out[gidx] = x[gidx] + asc * acc;
        }
    }
}

extern "C" void kernel_launch(void* const* d_in, const int* in_sizes, int n_in,
                              void* d_out, int out_size, void* d_ws, size_t ws_size,
                              hipStream_t stream) {
    const float* x     = (const float*)d_in[0];
    const float* nw    = (const float*)d_in[1];
    const float* nb    = (const float*)d_in[2];
    const float* qkvw  = (const float*)d_in[3];
    const float* projw = (const float*)d_in[4];
    const float* asc   = (const float*)d_in[5];
    const float* rpb   = (const float*)d_in[6];

    const int H = 256, W = 256;
    const int B = in_sizes[0] / (CH * H * W);
    const int nwin = B * (H / WSZ) * (W / WSZ);

    win_attn<<<nwin, 256, 0, stream>>>(x, nw, nb, qkvw, projw, asc, rpb,
                                       (float*)d_out, B, H, W);
}

// Round 3
// 436.866 us; speedup vs baseline: 3.2823x; 3.2823x over previous
//
#include <hip/hip_runtime.h>

#define WSZ 8
#define NHE 4
#define CH 64
#define NT 64
#define HD 16

typedef unsigned short u16;
typedef __attribute__((ext_vector_type(8))) short short8;
typedef __attribute__((ext_vector_type(4))) short short4v;
typedef __attribute__((ext_vector_type(4))) float float4v;

__device__ __forceinline__ u16 f2bf(float f) {
    unsigned u = __float_as_uint(f);
    u += 0x7fff + ((u >> 16) & 1);   // round-to-nearest-even
    return (u16)(u >> 16);
}
// XOR swizzle for [row][64] bf16 arrays: keeps 8-elem (16B) chunks intact,
// spreads the 8 chunk slots across banks by row.
__device__ __forceinline__ int SW(int row, int col) {
    return row * 64 + (col ^ ((row & 7) << 3));
}

#define MFMA(a, b, c) __builtin_amdgcn_mfma_f32_16x16x32_bf16(a, b, c, 0, 0, 0)

// One block per 8x8 window; 4 waves.
// MFMA layouts (gfx950 16x16x32): A[m=lane&15][k=quad*8+j], B[k=quad*8+j][n=lane&15],
// D: col=lane&15, row=quad*4+reg.
// LDS (52752 B -> 3 blocks/CU):
//   XS  fp32 [64ch][64tok] raw x (kept for residual)
//   XN  bf16 [64tok][64ch] swizzled; aliased by per-wave P after QKV
//   QO  bf16 [64tok][64ch] Q; aliased by O tile-by-tile during PV (safe: wave h
//       only touches cols h*16..h*16+15 and writes O[mt] after reading Q[mt])
//   KS  bf16 [64tok][64ch] K (LN scratch aliases this region pre-QKV)
//   VS  bf16 [64ch][64tok] V (tok-major so PV B-frags are contiguous)
__global__ __launch_bounds__(256, 3) void win_attn(
    const float* __restrict__ x, const float* __restrict__ nw, const float* __restrict__ nb,
    const float* __restrict__ qkvw, const float* __restrict__ projw,
    const float* __restrict__ ascale, const float* __restrict__ rpb,
    float* __restrict__ out, int B, int H, int W)
{
    const int HWsz = H * W;
    const int nww = W / WSZ, nwh = H / WSZ;
    const int win = blockIdx.x;
    const int ww = win % nww;
    const int t1 = win / nww;
    const int wh = t1 % nwh;
    const int b  = t1 / nwh;

    const int tid  = threadIdx.x;
    const int lane = tid & 63;
    const int wv   = tid >> 6;
    const int q    = lane >> 4;   // quad
    const int nl   = lane & 15;

    __shared__ alignas(16) char smem[52752];
    float* XS  = (float*)(smem);              // 16384 B
    u16*   XN  = (u16*)(smem + 16384);        // 8192 B (later: P, 2KB/wave)
    u16*   QO  = (u16*)(smem + 24576);        // 8192 B
    u16*   KS  = (u16*)(smem + 32768);        // 8192 B
    u16*   VS  = (u16*)(smem + 40960);        // 8192 B
    float* RPB = (float*)(smem + 49152);      // 3600 B
    float* PS  = (float*)(smem + 32768);      // LN scratch (aliases KS, dead before QKV)
    float* PS2 = PS + 256;
    float* MUs = PS + 512;
    float* RSs = PS + 576;

    const int rowbase = (wh * WSZ) * W + ww * WSZ;
    const float* xw = x + (size_t)b * CH * HWsz + rowbase;

    // ---- phase 0: x window -> XS [ch][tok], float4; stage rpb ----
    for (int e = tid; e < 1024; e += 256) {
        int c = e >> 4, r = e & 15;
        int i = r >> 1, j4 = (r & 1) * 4;
        float4v v = *(const float4v*)(xw + c * HWsz + i * W + j4);
        *(float4v*)&XS[c * 64 + i * 8 + j4] = v;
    }
    for (int e = tid; e < (2 * WSZ - 1) * (2 * WSZ - 1) * NHE; e += 256) RPB[e] = rpb[e];
    __syncthreads();

    // ---- phase 1: LayerNorm over channels (split across waves) ----
    {
        float s = 0.f, s2 = 0.f;
        #pragma unroll
        for (int ci = 0; ci < 16; ci++) {
            float v = XS[(wv * 16 + ci) * 64 + lane];
            s += v; s2 += v * v;
        }
        PS[wv * 64 + lane] = s;
        PS2[wv * 64 + lane] = s2;
    }
    __syncthreads();
    if (tid < 64) {
        float s  = PS[tid]  + PS[64 + tid]  + PS[128 + tid]  + PS[192 + tid];
        float s2 = PS2[tid] + PS2[64 + tid] + PS2[128 + tid] + PS2[192 + tid];
        float mu  = s * (1.f / 64.f);
        float var = s2 * (1.f / 64.f) - mu * mu;
        MUs[tid] = mu;
        RSs[tid] = rsqrtf(var + 1e-5f);
    }
    __syncthreads();
    {
        float mu = MUs[lane], rs = RSs[lane];
        #pragma unroll
        for (int ci = 0; ci < 16; ci++) {
            int c = wv * 16 + ci;                       // wave-uniform -> s_load nw/nb
            float v = (XS[c * 64 + lane] - mu) * rs * nw[c] + nb[c];
            XN[SW(lane, c)] = f2bf(v);
        }
    }
    __syncthreads();

    // ---- phase 2: QKV GEMM (M=64 tok, N=192, K=64), wave w owns n-tiles 3w..3w+2 ----
    {
        short8 afr[4][2];
        #pragma unroll
        for (int mt = 0; mt < 4; mt++)
            #pragma unroll
            for (int kt = 0; kt < 2; kt++) {
                int m = mt * 16 + nl;
                int phys = (kt * 4 + q) ^ (m & 7);
                afr[mt][kt] = *(short8*)&XN[m * 64 + phys * 8];
            }
        #pragma unroll
        for (int nt3 = 0; nt3 < 3; nt3++) {
            int nt = wv * 3 + nt3;
            short8 bfr[2];
            #pragma unroll
            for (int kt = 0; kt < 2; kt++) {
                const float* wp = qkvw + (nt * 16 + nl) * CH + kt * 32 + q * 8;
                float4v w0 = *(const float4v*)wp;
                float4v w1 = *(const float4v*)(wp + 4);
                short8 t;
                t[0] = (short)f2bf(w0.x); t[1] = (short)f2bf(w0.y);
                t[2] = (short)f2bf(w0.z); t[3] = (short)f2bf(w0.w);
                t[4] = (short)f2bf(w1.x); t[5] = (short)f2bf(w1.y);
                t[6] = (short)f2bf(w1.z); t[7] = (short)f2bf(w1.w);
                bfr[kt] = t;
            }
            int which = nt >> 2;                 // 0:Q 1:K 2:V (wave-uniform)
            int chb = (nt & 3) * 16 + nl;        // output channel within q/k/v
            #pragma unroll
            for (int mt = 0; mt < 4; mt++) {
                float4v acc = {0.f, 0.f, 0.f, 0.f};
                acc = MFMA(afr[mt][0], bfr[0], acc);
                acc = MFMA(afr[mt][1], bfr[1], acc);
                int tok0 = mt * 16 + q * 4;
                if (which == 0) {
                    #pragma unroll
                    for (int r = 0; r < 4; r++) QO[SW(tok0 + r, chb)] = f2bf(acc[r]);
                } else if (which == 1) {
                    #pragma unroll
                    for (int r = 0; r < 4; r++) KS[SW(tok0 + r, chb)] = f2bf(acc[r]);
                } else {
                    short4v pk;
                    pk[0] = (short)f2bf(acc[0]); pk[1] = (short)f2bf(acc[1]);
                    pk[2] = (short)f2bf(acc[2]); pk[3] = (short)f2bf(acc[3]);
                    int pt = tok0 ^ ((chb & 7) << 3);    // V is [ch][tok]: 4 toks contiguous
                    *(short4v*)&VS[chb * 64 + pt] = pk;
                }
            }
        }
    }
    __syncthreads();

    // ---- phase 3: attention, wave = head h; K=16 zero-padded to MFMA K=32 ----
    {
        const int h = wv;
        u16* Pw = XN + wv * 1024;   // per-wave P [16][64] bf16 (XN dead)
        const short8 zero8 = {0, 0, 0, 0, 0, 0, 0, 0};
        short8 kfr[4], vfr[2];
        #pragma unroll
        for (int nt = 0; nt < 4; nt++) {
            if (q < 2) {
                int n = nt * 16 + nl;
                int phys = (h * 2 + q) ^ (n & 7);
                kfr[nt] = *(short8*)&KS[n * 64 + phys * 8];
            } else kfr[nt] = zero8;
        }
        #pragma unroll
        for (int kt = 0; kt < 2; kt++) {
            int c = h * 16 + nl;
            int phys = (kt * 4 + q) ^ (c & 7);
            vfr[kt] = *(short8*)&VS[c * 64 + phys * 8];
        }
        #pragma unroll
        for (int mt = 0; mt < 4; mt++) {
            short8 qf;
            if (q < 2) {
                int m = mt * 16 + nl;
                int phys = (h * 2 + q) ^ (m & 7);
                qf = *(short8*)&QO[m * 64 + phys * 8];
            } else qf = zero8;
            float4v sacc[4];
            #pragma unroll
            for (int nt = 0; nt < 4; nt++) {
                float4v z = {0.f, 0.f, 0.f, 0.f};
                sacc[nt] = MFMA(qf, kfr[nt], z);
            }
            float sv[4][4], mx[4], sum[4], inv[4];
            #pragma unroll
            for (int r = 0; r < 4; r++) mx[r] = -1e30f;
            #pragma unroll
            for (int nt = 0; nt < 4; nt++) {
                int tokn = nt * 16 + nl;
                int i2 = tokn >> 3, j2 = tokn & 7;
                #pragma unroll
                for (int r = 0; r < 4; r++) {
                    int tokm = mt * 16 + q * 4 + r;
                    int i1 = tokm >> 3, j1 = tokm & 7;
                    float bias = RPB[((i1 - i2 + 7) * 15 + (j1 - j2 + 7)) * NHE + h];
                    float s = sacc[nt][r] * 0.25f + bias;   // hd^-0.5 = 0.25
                    sv[nt][r] = s;
                    mx[r] = fmaxf(mx[r], s);
                }
            }
            #pragma unroll
            for (int r = 0; r < 4; r++) {
                #pragma unroll
                for (int msk = 1; msk <= 8; msk <<= 1)
                    mx[r] = fmaxf(mx[r], __shfl_xor(mx[r], msk, 64));
                sum[r] = 0.f;
            }
            #pragma unroll
            for (int nt = 0; nt < 4; nt++)
                #pragma unroll
                for (int r = 0; r < 4; r++) {
                    float e = __expf(sv[nt][r] - mx[r]);
                    sv[nt][r] = e;
                    sum[r] += e;
                }
            #pragma unroll
            for (int r = 0; r < 4; r++) {
                #pragma unroll
                for (int msk = 1; msk <= 8; msk <<= 1)
                    sum[r] += __shfl_xor(sum[r], msk, 64);
                inv[r] = 1.f / sum[r];
            }
            #pragma unroll
            for (int nt = 0; nt < 4; nt++)
                #pragma unroll
                for (int r = 0; r < 4; r++)
                    Pw[SW(q * 4 + r, nt * 16 + nl)] = f2bf(sv[nt][r] * inv[r]);
            // PV: O[mt] = P[16x64] @ V[64x16]  (per-wave LDS, DS ops in-order per wave)
            float4v oacc = {0.f, 0.f, 0.f, 0.f};
            #pragma unroll
            for (int kt = 0; kt < 2; kt++) {
                int phys = (kt * 4 + q) ^ (nl & 7);
                short8 pf = *(short8*)&Pw[nl * 64 + phys * 8];
                oacc = MFMA(pf, vfr[kt], oacc);
            }
            #pragma unroll
            for (int r = 0; r < 4; r++)
                QO[SW(mt * 16 + q * 4 + r, h * 16 + nl)] = f2bf(oacc[r]);
        }
    }
    __syncthreads();

    // ---- phase 4: proj + residual; wave w owns out-channel tile w ----
    {
        const float asc = ascale[0];
        short8 wfr[2];
        #pragma unroll
        for (int kt = 0; kt < 2; kt++) {
            const float* wp = projw + (wv * 16 + nl) * CH + kt * 32 + q * 8;
            float4v w0 = *(const float4v*)wp;
            float4v w1 = *(const float4v*)(wp + 4);
            short8 t;
            t[0] = (short)f2bf(w0.x); t[1] = (short)f2bf(w0.y);
            t[2] = (short)f2bf(w0.z); t[3] = (short)f2bf(w0.w);
            t[4] = (short)f2bf(w1.x); t[5] = (short)f2bf(w1.y);
            t[6] = (short)f2bf(w1.z); t[7] = (short)f2bf(w1.w);
            wfr[kt] = t;
        }
        const int ch = wv * 16 + nl;
        float* outp = out + ((size_t)b * CH + ch) * HWsz + rowbase;
        #pragma unroll
        for (int mt = 0; mt < 4; mt++) {
            float4v yacc = {0.f, 0.f, 0.f, 0.f};
            #pragma unroll
            for (int kt = 0; kt < 2; kt++) {
                int m = mt * 16 + nl;
                int phys = (kt * 4 + q) ^ (m & 7);
                short8 of = *(short8*)&QO[m * 64 + phys * 8];
                yacc = MFMA(of, wfr[kt], yacc);
            }
            int tok0 = mt * 16 + q * 4;                  // 4 consecutive tokens = 4 consecutive j
            float4v xr = *(float4v*)&XS[ch * 64 + tok0]; // residual from LDS (no global re-read)
            int i = tok0 >> 3, j = tok0 & 7;
            float4v y;
            y[0] = xr[0] + asc * yacc[0];
            y[1] = xr[1] + asc * yacc[1];
            y[2] = xr[2] + asc * yacc[2];
            y[3] = xr[3] + asc * yacc[3];
            *(float4v*)(outp + i * W + j) = y;
        }
    }
}

extern "C" void kernel_launch(void* const* d_in, const int* in_sizes, int n_in,
                              void* d_out, int out_size, void* d_ws, size_t ws_size,
                              hipStream_t stream) {
    const float* x     = (const float*)d_in[0];
    const float* nw    = (const float*)d_in[1];
    const float* nb    = (const float*)d_in[2];
    const float* qkvw  = (const float*)d_in[3];
    const float* projw = (const float*)d_in[4];
    const float* asc   = (const float*)d_in[5];
    const float* rpb   = (const float*)d_in[6];

    const int H = 256, W = 256;
    const int B = in_sizes[0] / (CH * H * W);
    const int nwin = B * (H / WSZ) * (W / WSZ);

    win_attn<<<nwin, 256, 0, stream>>>(x, nw, nb, qkvw, projw, asc, rpb,
                                       (float*)d_out, B, H, W);
}